// Round 4
// baseline (261.572 us; speedup 1.0000x reference)
//
#include <hip/hip_runtime.h>

// LSS voxel pooling: B=2,N=6,D=48,FH=16,FW=44,C=80 -> out [2,80,1,256,256]
//
// R9: R8's cooperative fused kernel hung the container (hipGraph capture +
// grid.sync is a deadlock; cooperative launch is NOT graph-capturable).
// Permanent rule: grid sync == dispatch boundary.
// Keep R7's proven init+geom structure, but delete the reduce kernel:
// gather walks per-voxel entry lists (slice|w|mask meta) and reads x
// DIRECTLY -- no P round-trip (16MB), one fewer dispatch (+tail). Chains
// staged to LDS once per 64-voxel tile (geometry: gx,gy depend only on
// (bn,d,w), not h => <=1 entry/col, hot voxels ~7-15 entries).
// Per-entry f32 h-sum (reference order) + f64 cross-entry accumulate.
//
// Numerics (verified R1-R7): f64 geometry seeded with bit-exact f32 frustum
// values + f32-valued bounds constants; trunc-toward-zero.

#define NCH       80
#define GRID_HW   65536    // 256*256
#define OUT_PER_B 5242880  // 80*65536
#define HSTRIDE   3520     // 44*80 floats between h rows
#define PTS_PER_BN 33792   // 48*16*44
#define CAP       32       // staged entries per voxel (overflow -> walk)

// workspace layout (bytes)
#define N_ENT_MAX 405504           // 25344 cols * 16 groups worst case
#define NEXT_OFF  0u               // N_ENT_MAX*4 = 1622016
#define HEAD_OFF  1622016u         // 131072*4   = 524288
#define CNT_OFF   2146304u         // 256
#define META_OFF  2146560u         // N_ENT_MAX*4 = 1622016
#define WS_NEED   3768576u

__device__ inline void inv3(const double a[9], double inv[9]) {
    double c00 =  a[4]*a[8] - a[5]*a[7];
    double c01 = -(a[3]*a[8] - a[5]*a[6]);
    double c02 =  a[3]*a[7] - a[4]*a[6];
    double det = a[0]*c00 + a[1]*c01 + a[2]*c02;
    double id  = 1.0/det;
    inv[0] = c00*id;
    inv[1] = (a[2]*a[7]-a[1]*a[8])*id;
    inv[2] = (a[1]*a[5]-a[2]*a[4])*id;
    inv[3] = c01*id;
    inv[4] = (a[0]*a[8]-a[2]*a[6])*id;
    inv[5] = (a[2]*a[3]-a[0]*a[5])*id;
    inv[6] = c02*id;
    inv[7] = (a[1]*a[6]-a[0]*a[7])*id;
    inv[8] = (a[0]*a[4]-a[1]*a[3])*id;
}

// o[0..8]=inv(post_rots), [9..17]=rots@inv(intrins), [18..20]=post_trans, [21..23]=trans
__device__ inline void prep_bn(const float* __restrict__ rots,
                               const float* __restrict__ trans,
                               const float* __restrict__ intrins,
                               const float* __restrict__ post_rots,
                               const float* __restrict__ post_trans,
                               int bn, double* o) {
    double pr[9], kk[9], rt[9], ipr[9], ik[9];
    #pragma unroll
    for (int i = 0; i < 9; i++) {
        pr[i] = (double)post_rots[bn*9 + i];
        kk[i] = (double)intrins[bn*9 + i];
        rt[i] = (double)rots[bn*9 + i];
    }
    inv3(pr, ipr);
    inv3(kk, ik);
    #pragma unroll
    for (int i = 0; i < 9; i++) o[i] = ipr[i];
    #pragma unroll
    for (int r = 0; r < 3; r++)
        #pragma unroll
        for (int c = 0; c < 3; c++)
            o[9 + r*3 + c] = rt[r*3+0]*ik[0*3+c] + rt[r*3+1]*ik[1*3+c] + rt[r*3+2]*ik[2*3+c];
    #pragma unroll
    for (int i = 0; i < 3; i++) o[18 + i] = (double)post_trans[bn*3 + i];
    #pragma unroll
    for (int i = 0; i < 3; i++) o[21 + i] = (double)trans[bn*3 + i];
}

__global__ void prep_kernel(const float* __restrict__ rots,
                            const float* __restrict__ trans,
                            const float* __restrict__ intrins,
                            const float* __restrict__ post_rots,
                            const float* __restrict__ post_trans,
                            double* __restrict__ tw) {
    int bn = threadIdx.x;
    if (bn >= 12) return;
    prep_bn(rots, trans, intrins, post_rots, post_trans, bn, tw + bn*24);
}

__global__ __launch_bounds__(256) void zero_kernel(float4* __restrict__ p, int n4) {
    int i = blockIdx.x * 256 + threadIdx.x;
    int stride = gridDim.x * 256;
    for (; i < n4; i += stride) p[i] = make_float4(0.f, 0.f, 0.f, 0.f);
}

__global__ __launch_bounds__(256) void init_heads(int* __restrict__ head, int* __restrict__ counter) {
    int i = blockIdx.x * 256 + threadIdx.x;
    if (i < 131072) head[i] = -1;
    if (i == 0) counter[0] = 0;
}

// ---- shared geometry: fills s_base (vox id = b*65536+gy*256+gx, or -1). ----
__device__ inline void geom_points(const double* __restrict__ t,
                                   int b, int d, int tid, int* s_base) {
    const float dsv = __fadd_rn(2.0f, __fmul_rn((float)(56.0 / 48.0), (float)d));
    for (int idx = tid; idx < 704; idx += 256) {
        const int h = idx / 44;
        const int w = idx - h * 44;
        float xsv = (w == 43) ? 703.0f : (float)((double)w * (703.0 / 43.0));
        float ysv = (float)(h * 17);
        double px = (double)xsv - t[18];
        double py = (double)ysv - t[19];
        double pz = (double)dsv - t[20];
        double q0 = t[0]*px + t[1]*py + t[2]*pz;
        double q1 = t[3]*px + t[4]*py + t[5]*pz;
        double q2 = t[6]*px + t[7]*py + t[8]*pz;
        q0 *= q2;
        q1 *= q2;
        double e0 = t[9]*q0  + t[10]*q1 + t[11]*q2 + t[21];
        double e1 = t[12]*q0 + t[13]*q1 + t[14]*q2 + t[22];
        double e2 = t[15]*q0 + t[16]*q1 + t[17]*q2 + t[23];
        const double lxy = (double)(-51.2f);
        const double dxy = (double)(0.4f);
        int gx = (int)((e0 - lxy) / dxy);
        int gy = (int)((e1 - lxy) / dxy);
        int gz = (int)((e2 - (double)(-10.0f)) / (double)(20.0f));
        int base = -1;
        if (gx >= 0 && gx < 256 && gy >= 0 && gy < 256 && gz == 0)
            base = (b << 16) | (gy << 8) | gx;
        s_base[idx] = base;
    }
}

// K1: geometry + per-column voxel-group build + list link.
// Emits per-entry packed meta: slice(10b)<<22 | w(6b)<<16 | mask(16b).
__global__ __launch_bounds__(256) void geom_groups(const float* __restrict__ rots,
                                                   const float* __restrict__ trans,
                                                   const float* __restrict__ intrins,
                                                   const float* __restrict__ post_rots,
                                                   const float* __restrict__ post_trans,
                                                   int* __restrict__ nxt,
                                                   int* __restrict__ head,
                                                   int* __restrict__ counter,
                                                   unsigned* __restrict__ ent_meta) {
    __shared__ double   s_t[24];
    __shared__ int      s_base[704];
    __shared__ int      s_gbase[704];    // [w*16+k]
    __shared__ unsigned s_gmask[704];    // [w*16+k]
    __shared__ int      s_gcount[44];
    __shared__ int      s_goff[44];
    __shared__ int      s_eb;

    const int tid   = threadIdx.x;
    const int slice = blockIdx.x;        // bn*48 + d
    const int bn    = slice / 48;
    const int d     = slice - bn * 48;
    const int b     = bn / 6;

    if (tid == 0)
        prep_bn(rots, trans, intrins, post_rots, post_trans, bn, s_t);
    __syncthreads();

    geom_points(s_t, b, d, tid, s_base);
    __syncthreads();

    // group the 16 h-rows of each column by voxel id (real data: 1 group/col)
    if (tid < 44) {
        int gb[16]; unsigned gm[16];
        int cnt = 0;
        #pragma unroll
        for (int h = 0; h < 16; h++) {
            int pb = s_base[h * 44 + tid];
            if (pb >= 0) {
                int j = 0;
                for (; j < cnt; j++) if (gb[j] == pb) break;
                if (j < cnt) gm[j] |= (1u << h);
                else { gb[cnt] = pb; gm[cnt] = (1u << h); cnt++; }
            }
        }
        s_gcount[tid] = cnt;
        for (int j = 0; j < cnt; j++) {
            s_gbase[tid * 16 + j] = gb[j];
            s_gmask[tid * 16 + j] = gm[j];
        }
    }
    __syncthreads();

    if (tid == 0) {
        int off = 0;
        for (int w = 0; w < 44; w++) { s_goff[w] = off; off += s_gcount[w]; }
        s_eb = atomicAdd(counter, off);   // reserve contiguous entry range
    }
    __syncthreads();

    if (tid < 44) {
        int off = s_goff[tid];
        int cnt = s_gcount[tid];
        for (int k = 0; k < cnt; k++) {
            int e = s_eb + off + k;
            ent_meta[e] = ((unsigned)slice << 22) | ((unsigned)tid << 16)
                        | (s_gmask[tid * 16 + k] & 0xFFFFu);
            nxt[e] = atomicExch(&head[s_gbase[tid * 16 + k]], e);
        }
    }
}

// per-entry masked h-sum in f32 (reference within-column order), added to f64 acc
__device__ inline void entry_accum(const float* __restrict__ x, unsigned m, int c4,
                                   double& dx, double& dy, double& dz, double& dw) {
    int slice   = (int)(m >> 22);
    int w       = (int)((m >> 16) & 63u);
    unsigned mm = m & 0xFFFFu;
    const float* xb = x + (size_t)(slice * 704 + w) * NCH + c4 * 4;
    float ax = 0.f, ay = 0.f, az = 0.f, aw = 0.f;
    #pragma unroll
    for (int h = 0; h < 16; h++) {
        float4 v = *(const float4*)(xb + h * HSTRIDE);
        float mk = (float)((mm >> h) & 1u);
        ax = fmaf(mk, v.x, ax);
        ay = fmaf(mk, v.y, ay);
        az = fmaf(mk, v.z, az);
        aw = fmaf(mk, v.w, aw);
    }
    dx += (double)ax; dy += (double)ay; dz += (double)az; dw += (double)aw;
}

// K2: per 64-voxel tile: stage entry chains to LDS, sum x rows directly,
// LDS transpose, dense coalesced out write (writes ALL of out; no zeroing).
__global__ __launch_bounds__(256, 4) void gather_direct(const float* __restrict__ x,
                                                        const int* __restrict__ nxt,
                                                        const int* __restrict__ head,
                                                        const unsigned* __restrict__ ent_meta,
                                                        float* __restrict__ out) {
    __shared__ float tile[64 * 81];
    __shared__ int   s_ent[64 * CAP];
    __shared__ int   s_cnt[64];
    __shared__ int   s_ovf[64];

    const int tid = threadIdx.x;
    const int b   = blockIdx.x >> 10;
    const int v0  = (blockIdx.x & 1023) * 64;

    // stage chains (parallel across 64 voxels; chains are short)
    if (tid < 64) {
        int e = head[(b << 16) + v0 + tid];
        int c = 0;
        while (e >= 0 && c < CAP) { s_ent[tid * CAP + c] = e; c++; e = nxt[e]; }
        s_cnt[tid] = c;
        s_ovf[tid] = e;   // -1 unless chain > CAP (not expected)
    }
    __syncthreads();

    // 64 vox * 20 c4-items = 1280 items, 5 passes
    #pragma unroll
    for (int i = 0; i < 5; i++) {
        int j  = i * 256 + tid;
        int v  = j / 20;
        int c4 = j - v * 20;
        double dx = 0.0, dy = 0.0, dz = 0.0, dw = 0.0;
        const int cnt = s_cnt[v];
        for (int k = 0; k < cnt; k++)
            entry_accum(x, ent_meta[s_ent[v * CAP + k]], c4, dx, dy, dz, dw);
        int e = s_ovf[v];
        while (e >= 0) {          // overflow continuation (rare/never)
            entry_accum(x, ent_meta[e], c4, dx, dy, dz, dw);
            e = nxt[e];
        }
        tile[v * 81 + c4 * 4 + 0] = (float)dx;
        tile[v * 81 + c4 * 4 + 1] = (float)dy;
        tile[v * 81 + c4 * 4 + 2] = (float)dz;
        tile[v * 81 + c4 * 4 + 3] = (float)dw;
    }
    __syncthreads();

    float* dst = out + (size_t)b * OUT_PER_B + v0;
    #pragma unroll
    for (int i = 0; i < 20; i++) {
        int k  = i * 256 + tid;
        int c  = k >> 6;                // 0..79
        int lv = k & 63;
        dst[(size_t)c * GRID_HW + lv] = tile[lv * 81 + c];  // 256B/wave-row
    }
}

// Fallback (ws too small): direct atomics into out (R3 structure).
__global__ __launch_bounds__(256) void scatter_direct_kernel(const float* __restrict__ x,
                                                             const double* __restrict__ ws,
                                                             float* __restrict__ out) {
    __shared__ int      s_base[704];
    __shared__ int      s_colbase[44];
    __shared__ unsigned s_mask[44];
    __shared__ unsigned s_fb[44];

    const int tid = threadIdx.x;
    const int bn  = blockIdx.x / 48;
    const int d   = blockIdx.x - bn * 48;
    const int b   = bn / 6;
    geom_points(ws + bn * 24, b, d, tid, s_base);
    __syncthreads();

    if (tid < 44) {
        int cb = -1; unsigned mm = 0, fb = 0;
        #pragma unroll
        for (int h = 0; h < 16; h++) {
            int pb = s_base[h * 44 + tid];
            if (pb >= 0) {
                if (cb < 0) cb = pb;
                if (pb == cb) mm |= (1u << h);
                else          fb |= (1u << h);
            }
        }
        s_colbase[tid] = cb;
        s_mask[tid]    = mm;
        s_fb[tid]      = fb;
    }
    __syncthreads();

    const float* xb0 = x + ((size_t)bn * PTS_PER_BN + (size_t)d * 704) * NCH;
    #pragma unroll
    for (int pass = 0; pass < 4; pass++) {
        int item = pass * 256 + tid;
        if (item >= 880) break;
        int w  = item / 20;
        int c4 = item - w * 20;
        unsigned mm = s_mask[w];
        unsigned fb = s_fb[w];
        if (!(mm | fb)) continue;
        const float* xb = xb0 + (size_t)w * NCH + c4 * 4;
        float ax = 0.f, ay = 0.f, az = 0.f, aw = 0.f;
        #pragma unroll
        for (int h = 0; h < 16; h++) {
            if ((mm >> h) & 1u) {
                float4 v = *(const float4*)(xb + h * HSTRIDE);
                ax += v.x; ay += v.y; az += v.z; aw += v.w;
            } else if ((fb >> h) & 1u) {
                float4 v = *(const float4*)(xb + h * HSTRIDE);
                int vb = s_base[h * 44 + w];
                float* o = out + (size_t)(vb >> 16) * OUT_PER_B + (vb & 65535);
                atomicAdd(o + (size_t)(c4*4 + 0) * GRID_HW, v.x);
                atomicAdd(o + (size_t)(c4*4 + 1) * GRID_HW, v.y);
                atomicAdd(o + (size_t)(c4*4 + 2) * GRID_HW, v.z);
                atomicAdd(o + (size_t)(c4*4 + 3) * GRID_HW, v.w);
            }
        }
        if (mm) {
            int vb = s_colbase[w];
            float* o = out + (size_t)(vb >> 16) * OUT_PER_B + (vb & 65535);
            atomicAdd(o + (size_t)(c4*4 + 0) * GRID_HW, ax);
            atomicAdd(o + (size_t)(c4*4 + 1) * GRID_HW, ay);
            atomicAdd(o + (size_t)(c4*4 + 2) * GRID_HW, az);
            atomicAdd(o + (size_t)(c4*4 + 3) * GRID_HW, aw);
        }
    }
}

extern "C" void kernel_launch(void* const* d_in, const int* in_sizes, int n_in,
                              void* d_out, int out_size, void* d_ws, size_t ws_size,
                              hipStream_t stream) {
    const float* x          = (const float*)d_in[0];
    const float* rots       = (const float*)d_in[1];
    const float* trans      = (const float*)d_in[2];
    const float* intrins    = (const float*)d_in[3];
    const float* post_rots  = (const float*)d_in[4];
    const float* post_trans = (const float*)d_in[5];
    float* out = (float*)d_out;

    if (ws_size >= (size_t)WS_NEED) {
        int*      nxt     = (int*)((char*)d_ws + NEXT_OFF);
        int*      head    = (int*)((char*)d_ws + HEAD_OFF);
        int*      counter = (int*)((char*)d_ws + CNT_OFF);
        unsigned* meta    = (unsigned*)((char*)d_ws + META_OFF);
        init_heads<<<512, 256, 0, stream>>>(head, counter);
        geom_groups<<<576, 256, 0, stream>>>(rots, trans, intrins,
                                             post_rots, post_trans,
                                             nxt, head, counter, meta);
        gather_direct<<<2048, 256, 0, stream>>>(x, nxt, head, meta, out);
    } else if (ws_size >= 12 * 24 * sizeof(double)) {
        double* tw = (double*)d_ws;
        zero_kernel<<<2560, 256, 0, stream>>>((float4*)out, out_size / 16);
        prep_kernel<<<1, 64, 0, stream>>>(rots, trans, intrins, post_rots, post_trans, tw);
        scatter_direct_kernel<<<576, 256, 0, stream>>>(x, tw, out);
    }
}

// Round 5
// 229.920 us; speedup vs baseline: 1.1377x; 1.1377x over previous
//
#include <hip/hip_runtime.h>

// LSS voxel pooling: B=2,N=6,D=48,FH=16,FW=44,C=80 -> out [2,80,1,256,256]
//
// R10: R9 profile (first counters on our kernel): gather_direct 100us,
// 1.08TB/s, occ 13.9% -- fusing the x-read into per-voxel tiles put ~all
// 130MB on the few hot tiles (most tiles own zero entries) and serialized
// chain x 16 h-loads per thread. Fix: restore the BALANCED per-entry
// reduce (x -> P, uniform 16xfloat4 per item, full occupancy), and make
// gather cheap: stage each voxel's chain to LDS ONCE per tile (kills R7's
// 20x pointer re-walk), then one float4 P-load per (entry,c4) -- P is 8MB,
// L2-resident. Predicted: reduce 25-35us @ >=4TB/s, gather 10-15us,
// total ~205.
//
// Numerics: f64 geometry seeded with bit-exact f32 frustum values +
// f32-valued bounds constants; trunc-toward-zero. Per-entry f32 h-sum
// (reference order), f64 across entries.

#define NCH       80
#define GRID_HW   65536    // 256*256
#define OUT_PER_B 5242880  // 80*65536
#define HSTRIDE   3520     // 44*80 floats between h rows
#define PTS_PER_BN 33792   // 48*16*44
#define CAP       32       // staged entries per voxel (overflow -> walk)

// workspace layout (bytes)
#define N_ENT_MAX 405504           // hard bound (25344 cols x 16 groups)
#define P_BYTES   129761280u       // N_ENT_MAX * 80 * 4
#define NEXT_OFF  129761280u       // + N_ENT_MAX*4 = 1622016
#define HEAD_OFF  131383296u       // + 131072*4   = 524288
#define CNT_OFF   131907584u       // + 256
#define META_OFF  131907840u       // + N_ENT_MAX*4 = 1622016
#define WS_NEED   133529856u

__device__ inline void inv3(const double a[9], double inv[9]) {
    double c00 =  a[4]*a[8] - a[5]*a[7];
    double c01 = -(a[3]*a[8] - a[5]*a[6]);
    double c02 =  a[3]*a[7] - a[4]*a[6];
    double det = a[0]*c00 + a[1]*c01 + a[2]*c02;
    double id  = 1.0/det;
    inv[0] = c00*id;
    inv[1] = (a[2]*a[7]-a[1]*a[8])*id;
    inv[2] = (a[1]*a[5]-a[2]*a[4])*id;
    inv[3] = c01*id;
    inv[4] = (a[0]*a[8]-a[2]*a[6])*id;
    inv[5] = (a[2]*a[3]-a[0]*a[5])*id;
    inv[6] = c02*id;
    inv[7] = (a[1]*a[6]-a[0]*a[7])*id;
    inv[8] = (a[0]*a[4]-a[1]*a[3])*id;
}

// o[0..8]=inv(post_rots), [9..17]=rots@inv(intrins), [18..20]=post_trans, [21..23]=trans
__device__ inline void prep_bn(const float* __restrict__ rots,
                               const float* __restrict__ trans,
                               const float* __restrict__ intrins,
                               const float* __restrict__ post_rots,
                               const float* __restrict__ post_trans,
                               int bn, double* o) {
    double pr[9], kk[9], rt[9], ipr[9], ik[9];
    #pragma unroll
    for (int i = 0; i < 9; i++) {
        pr[i] = (double)post_rots[bn*9 + i];
        kk[i] = (double)intrins[bn*9 + i];
        rt[i] = (double)rots[bn*9 + i];
    }
    inv3(pr, ipr);
    inv3(kk, ik);
    #pragma unroll
    for (int i = 0; i < 9; i++) o[i] = ipr[i];
    #pragma unroll
    for (int r = 0; r < 3; r++)
        #pragma unroll
        for (int c = 0; c < 3; c++)
            o[9 + r*3 + c] = rt[r*3+0]*ik[0*3+c] + rt[r*3+1]*ik[1*3+c] + rt[r*3+2]*ik[2*3+c];
    #pragma unroll
    for (int i = 0; i < 3; i++) o[18 + i] = (double)post_trans[bn*3 + i];
    #pragma unroll
    for (int i = 0; i < 3; i++) o[21 + i] = (double)trans[bn*3 + i];
}

__global__ void prep_kernel(const float* __restrict__ rots,
                            const float* __restrict__ trans,
                            const float* __restrict__ intrins,
                            const float* __restrict__ post_rots,
                            const float* __restrict__ post_trans,
                            double* __restrict__ tw) {
    int bn = threadIdx.x;
    if (bn >= 12) return;
    prep_bn(rots, trans, intrins, post_rots, post_trans, bn, tw + bn*24);
}

__global__ __launch_bounds__(256) void zero_kernel(float4* __restrict__ p, int n4) {
    int i = blockIdx.x * 256 + threadIdx.x;
    int stride = gridDim.x * 256;
    for (; i < n4; i += stride) p[i] = make_float4(0.f, 0.f, 0.f, 0.f);
}

__global__ __launch_bounds__(256) void init_heads(int* __restrict__ head, int* __restrict__ counter) {
    int i = blockIdx.x * 256 + threadIdx.x;
    if (i < 131072) head[i] = -1;
    if (i == 0) counter[0] = 0;
}

// ---- shared geometry: fills s_base (vox id = b*65536+gy*256+gx, or -1). ----
__device__ inline void geom_points(const double* __restrict__ t,
                                   int b, int d, int tid, int* s_base) {
    const float dsv = __fadd_rn(2.0f, __fmul_rn((float)(56.0 / 48.0), (float)d));
    for (int idx = tid; idx < 704; idx += 256) {
        const int h = idx / 44;
        const int w = idx - h * 44;
        float xsv = (w == 43) ? 703.0f : (float)((double)w * (703.0 / 43.0));
        float ysv = (float)(h * 17);
        double px = (double)xsv - t[18];
        double py = (double)ysv - t[19];
        double pz = (double)dsv - t[20];
        double q0 = t[0]*px + t[1]*py + t[2]*pz;
        double q1 = t[3]*px + t[4]*py + t[5]*pz;
        double q2 = t[6]*px + t[7]*py + t[8]*pz;
        q0 *= q2;
        q1 *= q2;
        double e0 = t[9]*q0  + t[10]*q1 + t[11]*q2 + t[21];
        double e1 = t[12]*q0 + t[13]*q1 + t[14]*q2 + t[22];
        double e2 = t[15]*q0 + t[16]*q1 + t[17]*q2 + t[23];
        const double lxy = (double)(-51.2f);
        const double dxy = (double)(0.4f);
        int gx = (int)((e0 - lxy) / dxy);
        int gy = (int)((e1 - lxy) / dxy);
        int gz = (int)((e2 - (double)(-10.0f)) / (double)(20.0f));
        int base = -1;
        if (gx >= 0 && gx < 256 && gy >= 0 && gy < 256 && gz == 0)
            base = (b << 16) | (gy << 8) | gx;
        s_base[idx] = base;
    }
}

// K1: geometry + per-column voxel-group build + list link.
// Emits per-entry packed meta: slice(10b)<<22 | w(6b)<<16 | mask(16b).
__global__ __launch_bounds__(256) void geom_groups(const float* __restrict__ rots,
                                                   const float* __restrict__ trans,
                                                   const float* __restrict__ intrins,
                                                   const float* __restrict__ post_rots,
                                                   const float* __restrict__ post_trans,
                                                   int* __restrict__ nxt,
                                                   int* __restrict__ head,
                                                   int* __restrict__ counter,
                                                   unsigned* __restrict__ ent_meta) {
    __shared__ double   s_t[24];
    __shared__ int      s_base[704];
    __shared__ int      s_gbase[704];    // [w*16+k]
    __shared__ unsigned s_gmask[704];    // [w*16+k]
    __shared__ int      s_gcount[44];
    __shared__ int      s_goff[44];
    __shared__ int      s_eb;

    const int tid   = threadIdx.x;
    const int slice = blockIdx.x;        // bn*48 + d
    const int bn    = slice / 48;
    const int d     = slice - bn * 48;
    const int b     = bn / 6;

    if (tid == 0)
        prep_bn(rots, trans, intrins, post_rots, post_trans, bn, s_t);
    __syncthreads();

    geom_points(s_t, b, d, tid, s_base);
    __syncthreads();

    // group the 16 h-rows of each column by voxel id (real data: 1 group/col)
    if (tid < 44) {
        int gb[16]; unsigned gm[16];
        int cnt = 0;
        #pragma unroll
        for (int h = 0; h < 16; h++) {
            int pb = s_base[h * 44 + tid];
            if (pb >= 0) {
                int j = 0;
                for (; j < cnt; j++) if (gb[j] == pb) break;
                if (j < cnt) gm[j] |= (1u << h);
                else { gb[cnt] = pb; gm[cnt] = (1u << h); cnt++; }
            }
        }
        s_gcount[tid] = cnt;
        for (int j = 0; j < cnt; j++) {
            s_gbase[tid * 16 + j] = gb[j];
            s_gmask[tid * 16 + j] = gm[j];
        }
    }
    __syncthreads();

    if (tid == 0) {
        int off = 0;
        for (int w = 0; w < 44; w++) { s_goff[w] = off; off += s_gcount[w]; }
        s_eb = atomicAdd(counter, off);   // reserve contiguous entry range
    }
    __syncthreads();

    if (tid < 44) {
        int off = s_goff[tid];
        int cnt = s_gcount[tid];
        for (int k = 0; k < cnt; k++) {
            int e = s_eb + off + k;
            ent_meta[e] = ((unsigned)slice << 22) | ((unsigned)tid << 16)
                        | (s_gmask[tid * 16 + k] & 0xFFFFu);
            nxt[e] = atomicExch(&head[s_gbase[tid * 16 + k]], e);
        }
    }
}

// K2: balanced streaming reduce x -> P. One item = (entry, c4); uniform
// 16x float4 loads (always in-bounds), fmaf-masked; full occupancy.
__global__ __launch_bounds__(256) void reduce_kernel(const float* __restrict__ x,
                                                     const unsigned* __restrict__ ent_meta,
                                                     const int* __restrict__ counter,
                                                     float* __restrict__ P) {
    const int NE = counter[0];
    const int total = NE * 20;
    int i = blockIdx.x * 256 + threadIdx.x;
    const int stride = gridDim.x * 256;
    for (; i < total; i += stride) {
        int e  = i / 20;
        int c4 = i - e * 20;
        unsigned meta = ent_meta[e];
        int slice   = (int)(meta >> 22);
        int w       = (int)((meta >> 16) & 63u);
        unsigned mm = meta & 0xFFFFu;
        const float* xb = x + (size_t)(slice * 704 + w) * NCH + c4 * 4;
        float ax = 0.f, ay = 0.f, az = 0.f, aw = 0.f;
        #pragma unroll
        for (int h = 0; h < 16; h++) {
            float4 v = *(const float4*)(xb + h * HSTRIDE);
            float m = (float)((mm >> h) & 1u);
            ax = fmaf(m, v.x, ax);
            ay = fmaf(m, v.y, ay);
            az = fmaf(m, v.z, az);
            aw = fmaf(m, v.w, aw);
        }
        float4 r; r.x = ax; r.y = ay; r.z = az; r.w = aw;
        *(float4*)(P + (size_t)e * NCH + c4 * 4) = r;   // 320B contiguous
    }
}

// K3: per 64-voxel tile: stage chains to LDS once, one float4 P-load per
// (entry,c4) (P is L2-resident), f64 across entries, LDS transpose,
// dense coalesced out write (writes ALL of out; no zeroing pass).
__global__ __launch_bounds__(256, 4) void gather_tiled(const float* __restrict__ P,
                                                       const int* __restrict__ nxt,
                                                       const int* __restrict__ head,
                                                       float* __restrict__ out) {
    __shared__ float tile[64 * 81];
    __shared__ int   s_ent[64 * CAP];
    __shared__ int   s_cnt[64];
    __shared__ int   s_ovf[64];

    const int tid = threadIdx.x;
    const int b   = blockIdx.x >> 10;
    const int v0  = (blockIdx.x & 1023) * 64;

    // stage chains once (parallel across 64 voxels; chains are short)
    if (tid < 64) {
        int e = head[(b << 16) + v0 + tid];
        int c = 0;
        while (e >= 0 && c < CAP) { s_ent[tid * CAP + c] = e; c++; e = nxt[e]; }
        s_cnt[tid] = c;
        s_ovf[tid] = e;   // -1 unless chain > CAP
    }
    __syncthreads();

    // 64 vox * 20 c4-items = 1280 items, 5 passes
    #pragma unroll
    for (int i = 0; i < 5; i++) {
        int j  = i * 256 + tid;
        int v  = j / 20;
        int c4 = j - v * 20;
        double dx = 0.0, dy = 0.0, dz = 0.0, dw = 0.0;
        const int cnt = s_cnt[v];
        for (int k = 0; k < cnt; k++) {
            const float4 p = *(const float4*)(P + (size_t)s_ent[v * CAP + k] * NCH + c4 * 4);
            dx += (double)p.x; dy += (double)p.y; dz += (double)p.z; dw += (double)p.w;
        }
        int e = s_ovf[v];
        while (e >= 0) {          // overflow continuation (rare/never)
            const float4 p = *(const float4*)(P + (size_t)e * NCH + c4 * 4);
            dx += (double)p.x; dy += (double)p.y; dz += (double)p.z; dw += (double)p.w;
            e = nxt[e];
        }
        tile[v * 81 + c4 * 4 + 0] = (float)dx;
        tile[v * 81 + c4 * 4 + 1] = (float)dy;
        tile[v * 81 + c4 * 4 + 2] = (float)dz;
        tile[v * 81 + c4 * 4 + 3] = (float)dw;
    }
    __syncthreads();

    float* dst = out + (size_t)b * OUT_PER_B + v0;
    #pragma unroll
    for (int i = 0; i < 20; i++) {
        int k  = i * 256 + tid;
        int c  = k >> 6;                // 0..79
        int lv = k & 63;
        dst[(size_t)c * GRID_HW + lv] = tile[lv * 81 + c];  // 256B/wave-row
    }
}

// Fallback (ws too small): direct atomics into out (R3 structure).
__global__ __launch_bounds__(256) void scatter_direct_kernel(const float* __restrict__ x,
                                                             const double* __restrict__ ws,
                                                             float* __restrict__ out) {
    __shared__ int      s_base[704];
    __shared__ int      s_colbase[44];
    __shared__ unsigned s_mask[44];
    __shared__ unsigned s_fb[44];

    const int tid = threadIdx.x;
    const int bn  = blockIdx.x / 48;
    const int d   = blockIdx.x - bn * 48;
    const int b   = bn / 6;
    geom_points(ws + bn * 24, b, d, tid, s_base);
    __syncthreads();

    if (tid < 44) {
        int cb = -1; unsigned mm = 0, fb = 0;
        #pragma unroll
        for (int h = 0; h < 16; h++) {
            int pb = s_base[h * 44 + tid];
            if (pb >= 0) {
                if (cb < 0) cb = pb;
                if (pb == cb) mm |= (1u << h);
                else          fb |= (1u << h);
            }
        }
        s_colbase[tid] = cb;
        s_mask[tid]    = mm;
        s_fb[tid]      = fb;
    }
    __syncthreads();

    const float* xb0 = x + ((size_t)bn * PTS_PER_BN + (size_t)d * 704) * NCH;
    #pragma unroll
    for (int pass = 0; pass < 4; pass++) {
        int item = pass * 256 + tid;
        if (item >= 880) break;
        int w  = item / 20;
        int c4 = item - w * 20;
        unsigned mm = s_mask[w];
        unsigned fb = s_fb[w];
        if (!(mm | fb)) continue;
        const float* xb = xb0 + (size_t)w * NCH + c4 * 4;
        float ax = 0.f, ay = 0.f, az = 0.f, aw = 0.f;
        #pragma unroll
        for (int h = 0; h < 16; h++) {
            if ((mm >> h) & 1u) {
                float4 v = *(const float4*)(xb + h * HSTRIDE);
                ax += v.x; ay += v.y; az += v.z; aw += v.w;
            } else if ((fb >> h) & 1u) {
                float4 v = *(const float4*)(xb + h * HSTRIDE);
                int vb = s_base[h * 44 + w];
                float* o = out + (size_t)(vb >> 16) * OUT_PER_B + (vb & 65535);
                atomicAdd(o + (size_t)(c4*4 + 0) * GRID_HW, v.x);
                atomicAdd(o + (size_t)(c4*4 + 1) * GRID_HW, v.y);
                atomicAdd(o + (size_t)(c4*4 + 2) * GRID_HW, v.z);
                atomicAdd(o + (size_t)(c4*4 + 3) * GRID_HW, v.w);
            }
        }
        if (mm) {
            int vb = s_colbase[w];
            float* o = out + (size_t)(vb >> 16) * OUT_PER_B + (vb & 65535);
            atomicAdd(o + (size_t)(c4*4 + 0) * GRID_HW, ax);
            atomicAdd(o + (size_t)(c4*4 + 1) * GRID_HW, ay);
            atomicAdd(o + (size_t)(c4*4 + 2) * GRID_HW, az);
            atomicAdd(o + (size_t)(c4*4 + 3) * GRID_HW, aw);
        }
    }
}

extern "C" void kernel_launch(void* const* d_in, const int* in_sizes, int n_in,
                              void* d_out, int out_size, void* d_ws, size_t ws_size,
                              hipStream_t stream) {
    const float* x          = (const float*)d_in[0];
    const float* rots       = (const float*)d_in[1];
    const float* trans      = (const float*)d_in[2];
    const float* intrins    = (const float*)d_in[3];
    const float* post_rots  = (const float*)d_in[4];
    const float* post_trans = (const float*)d_in[5];
    float* out = (float*)d_out;

    if (ws_size >= (size_t)WS_NEED) {
        float*    P       = (float*)d_ws;
        int*      nxt     = (int*)((char*)d_ws + NEXT_OFF);
        int*      head    = (int*)((char*)d_ws + HEAD_OFF);
        int*      counter = (int*)((char*)d_ws + CNT_OFF);
        unsigned* meta    = (unsigned*)((char*)d_ws + META_OFF);
        init_heads<<<512, 256, 0, stream>>>(head, counter);
        geom_groups<<<576, 256, 0, stream>>>(rots, trans, intrins,
                                             post_rots, post_trans,
                                             nxt, head, counter, meta);
        reduce_kernel<<<2048, 256, 0, stream>>>(x, meta, counter, P);
        gather_tiled<<<2048, 256, 0, stream>>>(P, nxt, head, out);
    } else if (ws_size >= 12 * 24 * sizeof(double)) {
        double* tw = (double*)d_ws;
        zero_kernel<<<2560, 256, 0, stream>>>((float4*)out, out_size / 16);
        prep_kernel<<<1, 64, 0, stream>>>(rots, trans, intrins, post_rots, post_trans, tw);
        scatter_direct_kernel<<<576, 256, 0, stream>>>(x, tw, out);
    }
}

// Round 6
// 224.832 us; speedup vs baseline: 1.1634x; 1.0226x over previous
//
#include <hip/hip_runtime.h>

// LSS voxel pooling: B=2,N=6,D=48,FH=16,FW=44,C=80 -> out [2,80,1,256,256]
//
// R11: R10 hit 229.9 (best). Decomposition: ~151us harness fills + ours
// ~78us. True traffic floor of ours ~19us (R9 counters: only 65.8MB of x
// is in-bounds). Squeeze phases:
//  - geom_cols: 1 thread/column (99 blk x 256 = 25344 exactly), per-block
//    LDS transforms, run-length group dedup over static vox[16] (no
//    scratch), wave-aggregated alloc (1 atomic/wave).
//  - gather: f32 accum, CAP 16, LDS 25.3KB, lb(256,6) = 6 blocks/CU.
//  - init: int4, 128 blocks.
//  - reduce: unchanged (balanced, coalesced), 1024 blocks.
//
// Numerics: f64 geometry seeded with bit-exact f32 frustum values +
// f32-valued bounds constants; trunc-toward-zero. Per-entry f32 h-sum in
// reference order; f32 across entries (validated R6/R7/R10, <=0.0625).
// Run-length grouping may split a voxel's h-rows into 2 entries when
// non-adjacent -- both link to the same head => still summed (correct).

#define NCH       80
#define GRID_HW   65536    // 256*256
#define OUT_PER_B 5242880  // 80*65536
#define HSTRIDE   3520     // 44*80 floats between h rows
#define PTS_PER_BN 33792   // 48*16*44
#define NCOLS     25344    // 576 slices * 44 cols
#define CAP       16       // staged entries per voxel (overflow -> walk)

// workspace layout (bytes)
#define N_ENT_MAX 405504           // 25344 cols x 16 groups worst case
#define P_BYTES   129761280u       // N_ENT_MAX * 80 * 4
#define NEXT_OFF  129761280u       // + N_ENT_MAX*4 = 1622016
#define HEAD_OFF  131383296u       // + 131072*4   = 524288
#define CNT_OFF   131907584u       // + 256
#define META_OFF  131907840u       // + N_ENT_MAX*4 = 1622016
#define WS_NEED   133529856u

__device__ inline void inv3(const double a[9], double inv[9]) {
    double c00 =  a[4]*a[8] - a[5]*a[7];
    double c01 = -(a[3]*a[8] - a[5]*a[6]);
    double c02 =  a[3]*a[7] - a[4]*a[6];
    double det = a[0]*c00 + a[1]*c01 + a[2]*c02;
    double id  = 1.0/det;
    inv[0] = c00*id;
    inv[1] = (a[2]*a[7]-a[1]*a[8])*id;
    inv[2] = (a[1]*a[5]-a[2]*a[4])*id;
    inv[3] = c01*id;
    inv[4] = (a[0]*a[8]-a[2]*a[6])*id;
    inv[5] = (a[2]*a[3]-a[0]*a[5])*id;
    inv[6] = c02*id;
    inv[7] = (a[1]*a[6]-a[0]*a[7])*id;
    inv[8] = (a[0]*a[4]-a[1]*a[3])*id;
}

// o[0..8]=inv(post_rots), [9..17]=rots@inv(intrins), [18..20]=post_trans, [21..23]=trans
__device__ inline void prep_bn(const float* __restrict__ rots,
                               const float* __restrict__ trans,
                               const float* __restrict__ intrins,
                               const float* __restrict__ post_rots,
                               const float* __restrict__ post_trans,
                               int bn, double* o) {
    double pr[9], kk[9], rt[9], ipr[9], ik[9];
    #pragma unroll
    for (int i = 0; i < 9; i++) {
        pr[i] = (double)post_rots[bn*9 + i];
        kk[i] = (double)intrins[bn*9 + i];
        rt[i] = (double)rots[bn*9 + i];
    }
    inv3(pr, ipr);
    inv3(kk, ik);
    #pragma unroll
    for (int i = 0; i < 9; i++) o[i] = ipr[i];
    #pragma unroll
    for (int r = 0; r < 3; r++)
        #pragma unroll
        for (int c = 0; c < 3; c++)
            o[9 + r*3 + c] = rt[r*3+0]*ik[0*3+c] + rt[r*3+1]*ik[1*3+c] + rt[r*3+2]*ik[2*3+c];
    #pragma unroll
    for (int i = 0; i < 3; i++) o[18 + i] = (double)post_trans[bn*3 + i];
    #pragma unroll
    for (int i = 0; i < 3; i++) o[21 + i] = (double)trans[bn*3 + i];
}

__global__ void prep_kernel(const float* __restrict__ rots,
                            const float* __restrict__ trans,
                            const float* __restrict__ intrins,
                            const float* __restrict__ post_rots,
                            const float* __restrict__ post_trans,
                            double* __restrict__ tw) {
    int bn = threadIdx.x;
    if (bn >= 12) return;
    prep_bn(rots, trans, intrins, post_rots, post_trans, bn, tw + bn*24);
}

__global__ __launch_bounds__(256) void zero_kernel(float4* __restrict__ p, int n4) {
    int i = blockIdx.x * 256 + threadIdx.x;
    int stride = gridDim.x * 256;
    for (; i < n4; i += stride) p[i] = make_float4(0.f, 0.f, 0.f, 0.f);
}

// 131072 heads as 32768 int4 stores; 128 blocks x 256 = one store/thread.
__global__ __launch_bounds__(256) void init_heads(int4* __restrict__ head4, int* __restrict__ counter) {
    int i = blockIdx.x * 256 + threadIdx.x;
    head4[i] = make_int4(-1, -1, -1, -1);
    if (i == 0) counter[0] = 0;
}

// K1: one thread per column. Transforms in LDS (12 threads compute),
// 16 h-points per thread (static vox[16]), run-length grouping,
// wave-aggregated entry allocation, list link.
__global__ __launch_bounds__(256) void geom_cols(const float* __restrict__ rots,
                                                 const float* __restrict__ trans,
                                                 const float* __restrict__ intrins,
                                                 const float* __restrict__ post_rots,
                                                 const float* __restrict__ post_trans,
                                                 int* __restrict__ nxt,
                                                 int* __restrict__ head,
                                                 int* __restrict__ counter,
                                                 unsigned* __restrict__ ent_meta) {
    __shared__ double s_t[12 * 24];

    const int tid  = threadIdx.x;
    const int col  = blockIdx.x * 256 + tid;      // 99*256 == 25344 exactly
    const int lane = tid & 63;

    if (tid < 12)
        prep_bn(rots, trans, intrins, post_rots, post_trans, tid, s_t + tid * 24);
    __syncthreads();

    const int slice = col / 44;                   // bn*48 + d
    const int w     = col - slice * 44;
    const int bn    = slice / 48;
    const int d     = slice - bn * 48;
    const int b     = bn / 6;
    const double* t = s_t + bn * 24;

    // per-h voxel ids (statically indexed -> registers)
    int vox[16];
    {
        const float dsv = __fadd_rn(2.0f, __fmul_rn((float)(56.0 / 48.0), (float)d));
        const float xsv = (w == 43) ? 703.0f : (float)((double)w * (703.0 / 43.0));
        const double px = (double)xsv - t[18];
        #pragma unroll
        for (int h = 0; h < 16; h++) {
            float ysv = (float)(h * 17);
            double py = (double)ysv - t[19];
            double pz = (double)dsv - t[20];
            double q0 = t[0]*px + t[1]*py + t[2]*pz;
            double q1 = t[3]*px + t[4]*py + t[5]*pz;
            double q2 = t[6]*px + t[7]*py + t[8]*pz;
            q0 *= q2;
            q1 *= q2;
            double e0 = t[9]*q0  + t[10]*q1 + t[11]*q2 + t[21];
            double e1 = t[12]*q0 + t[13]*q1 + t[14]*q2 + t[22];
            double e2 = t[15]*q0 + t[16]*q1 + t[17]*q2 + t[23];
            const double lxy = (double)(-51.2f);
            const double dxy = (double)(0.4f);
            int gx = (int)((e0 - lxy) / dxy);
            int gy = (int)((e1 - lxy) / dxy);
            int gz = (int)((e2 - (double)(-10.0f)) / (double)(20.0f));
            vox[h] = (gx >= 0 && gx < 256 && gy >= 0 && gy < 256 && gz == 0)
                   ? ((b << 16) | (gy << 8) | gx) : -1;
        }
    }

    // count run-length groups (break at -1 or id change)
    int cnt = 0;
    #pragma unroll
    for (int h = 0; h < 16; h++) {
        int prev = (h == 0) ? -1 : vox[h - 1];
        if (vox[h] >= 0 && vox[h] != prev) cnt++;
    }

    // wave-aggregated allocation (1 atomic per wave)
    int pre = cnt;
    #pragma unroll
    for (int off = 1; off < 64; off <<= 1) {
        int n = __shfl_up(pre, off);
        if (lane >= off) pre += n;
    }
    int wtot  = __shfl(pre, 63);
    int wbase = 0;
    if (wtot > 0) {
        if (lane == 63) wbase = atomicAdd(counter, wtot);
        wbase = __shfl(wbase, 63);
    }
    int e = wbase + pre - cnt;    // my first entry index

    // emit run-length groups
    int cur = -1; unsigned mask = 0;
    #pragma unroll
    for (int h = 0; h < 16; h++) {
        if (vox[h] < 0) {
            if (cur >= 0) {
                ent_meta[e] = ((unsigned)slice << 22) | ((unsigned)w << 16) | mask;
                nxt[e] = atomicExch(&head[cur], e);
                e++; cur = -1; mask = 0;
            }
        } else if (vox[h] != cur) {
            if (cur >= 0) {
                ent_meta[e] = ((unsigned)slice << 22) | ((unsigned)w << 16) | mask;
                nxt[e] = atomicExch(&head[cur], e);
                e++;
            }
            cur = vox[h]; mask = (1u << h);
        } else {
            mask |= (1u << h);
        }
    }
    if (cur >= 0) {
        ent_meta[e] = ((unsigned)slice << 22) | ((unsigned)w << 16) | mask;
        nxt[e] = atomicExch(&head[cur], e);
    }
}

// K2: balanced streaming reduce x -> P. One item = (entry, c4); uniform
// 16x float4 loads (always in-bounds), fmaf-masked; full occupancy.
__global__ __launch_bounds__(256) void reduce_kernel(const float* __restrict__ x,
                                                     const unsigned* __restrict__ ent_meta,
                                                     const int* __restrict__ counter,
                                                     float* __restrict__ P) {
    const int NE = counter[0];
    const int total = NE * 20;
    int i = blockIdx.x * 256 + threadIdx.x;
    const int stride = gridDim.x * 256;
    for (; i < total; i += stride) {
        int e  = i / 20;
        int c4 = i - e * 20;
        unsigned meta = ent_meta[e];
        int slice   = (int)(meta >> 22);
        int w       = (int)((meta >> 16) & 63u);
        unsigned mm = meta & 0xFFFFu;
        const float* xb = x + (size_t)(slice * 704 + w) * NCH + c4 * 4;
        float ax = 0.f, ay = 0.f, az = 0.f, aw = 0.f;
        #pragma unroll
        for (int h = 0; h < 16; h++) {
            float4 v = *(const float4*)(xb + h * HSTRIDE);
            float m = (float)((mm >> h) & 1u);
            ax = fmaf(m, v.x, ax);
            ay = fmaf(m, v.y, ay);
            az = fmaf(m, v.z, az);
            aw = fmaf(m, v.w, aw);
        }
        float4 r; r.x = ax; r.y = ay; r.z = az; r.w = aw;
        *(float4*)(P + (size_t)e * NCH + c4 * 4) = r;   // 320B contiguous
    }
}

// K3: per 64-voxel tile: stage chains to LDS once, one float4 P-load per
// (entry,c4) (P is L2-resident), f32 across entries, LDS transpose,
// dense coalesced out write (writes ALL of out; no zeroing pass).
__global__ __launch_bounds__(256, 6) void gather_tiled(const float* __restrict__ P,
                                                       const int* __restrict__ nxt,
                                                       const int* __restrict__ head,
                                                       float* __restrict__ out) {
    __shared__ float tile[64 * 81];
    __shared__ int   s_ent[64 * CAP];
    __shared__ int   s_cnt[64];
    __shared__ int   s_ovf[64];

    const int tid = threadIdx.x;
    const int b   = blockIdx.x >> 10;
    const int v0  = (blockIdx.x & 1023) * 64;

    // stage chains once (parallel across 64 voxels; chains are short)
    if (tid < 64) {
        int e = head[(b << 16) + v0 + tid];
        int c = 0;
        while (e >= 0 && c < CAP) { s_ent[tid * CAP + c] = e; c++; e = nxt[e]; }
        s_cnt[tid] = c;
        s_ovf[tid] = e;   // -1 unless chain > CAP
    }
    __syncthreads();

    // 64 vox * 20 c4-items = 1280 items, 5 passes
    #pragma unroll
    for (int i = 0; i < 5; i++) {
        int j  = i * 256 + tid;
        int v  = j / 20;
        int c4 = j - v * 20;
        float ax = 0.f, ay = 0.f, az = 0.f, aw = 0.f;
        const int cnt = s_cnt[v];
        for (int k = 0; k < cnt; k++) {
            const float4 p = *(const float4*)(P + (size_t)s_ent[v * CAP + k] * NCH + c4 * 4);
            ax += p.x; ay += p.y; az += p.z; aw += p.w;
        }
        int e = s_ovf[v];
        while (e >= 0) {          // overflow continuation (rare/never)
            const float4 p = *(const float4*)(P + (size_t)e * NCH + c4 * 4);
            ax += p.x; ay += p.y; az += p.z; aw += p.w;
            e = nxt[e];
        }
        tile[v * 81 + c4 * 4 + 0] = ax;
        tile[v * 81 + c4 * 4 + 1] = ay;
        tile[v * 81 + c4 * 4 + 2] = az;
        tile[v * 81 + c4 * 4 + 3] = aw;
    }
    __syncthreads();

    float* dst = out + (size_t)b * OUT_PER_B + v0;
    #pragma unroll
    for (int i = 0; i < 20; i++) {
        int k  = i * 256 + tid;
        int c  = k >> 6;                // 0..79
        int lv = k & 63;
        dst[(size_t)c * GRID_HW + lv] = tile[lv * 81 + c];  // 256B/wave-row
    }
}

// ---- fallback path (ws too small): R3 structure ----
__device__ inline void geom_points(const double* __restrict__ t,
                                   int b, int d, int tid, int* s_base) {
    const float dsv = __fadd_rn(2.0f, __fmul_rn((float)(56.0 / 48.0), (float)d));
    for (int idx = tid; idx < 704; idx += 256) {
        const int h = idx / 44;
        const int w = idx - h * 44;
        float xsv = (w == 43) ? 703.0f : (float)((double)w * (703.0 / 43.0));
        float ysv = (float)(h * 17);
        double px = (double)xsv - t[18];
        double py = (double)ysv - t[19];
        double pz = (double)dsv - t[20];
        double q0 = t[0]*px + t[1]*py + t[2]*pz;
        double q1 = t[3]*px + t[4]*py + t[5]*pz;
        double q2 = t[6]*px + t[7]*py + t[8]*pz;
        q0 *= q2;
        q1 *= q2;
        double e0 = t[9]*q0  + t[10]*q1 + t[11]*q2 + t[21];
        double e1 = t[12]*q0 + t[13]*q1 + t[14]*q2 + t[22];
        double e2 = t[15]*q0 + t[16]*q1 + t[17]*q2 + t[23];
        const double lxy = (double)(-51.2f);
        const double dxy = (double)(0.4f);
        int gx = (int)((e0 - lxy) / dxy);
        int gy = (int)((e1 - lxy) / dxy);
        int gz = (int)((e2 - (double)(-10.0f)) / (double)(20.0f));
        int base = -1;
        if (gx >= 0 && gx < 256 && gy >= 0 && gy < 256 && gz == 0)
            base = (b << 16) | (gy << 8) | gx;
        s_base[idx] = base;
    }
}

__global__ __launch_bounds__(256) void scatter_direct_kernel(const float* __restrict__ x,
                                                             const double* __restrict__ ws,
                                                             float* __restrict__ out) {
    __shared__ int      s_base[704];
    __shared__ int      s_colbase[44];
    __shared__ unsigned s_mask[44];
    __shared__ unsigned s_fb[44];

    const int tid = threadIdx.x;
    const int bn  = blockIdx.x / 48;
    const int d   = blockIdx.x - bn * 48;
    const int b   = bn / 6;
    geom_points(ws + bn * 24, b, d, tid, s_base);
    __syncthreads();

    if (tid < 44) {
        int cb = -1; unsigned mm = 0, fb = 0;
        #pragma unroll
        for (int h = 0; h < 16; h++) {
            int pb = s_base[h * 44 + tid];
            if (pb >= 0) {
                if (cb < 0) cb = pb;
                if (pb == cb) mm |= (1u << h);
                else          fb |= (1u << h);
            }
        }
        s_colbase[tid] = cb;
        s_mask[tid]    = mm;
        s_fb[tid]      = fb;
    }
    __syncthreads();

    const float* xb0 = x + ((size_t)bn * PTS_PER_BN + (size_t)d * 704) * NCH;
    #pragma unroll
    for (int pass = 0; pass < 4; pass++) {
        int item = pass * 256 + tid;
        if (item >= 880) break;
        int w  = item / 20;
        int c4 = item - w * 20;
        unsigned mm = s_mask[w];
        unsigned fb = s_fb[w];
        if (!(mm | fb)) continue;
        const float* xb = xb0 + (size_t)w * NCH + c4 * 4;
        float ax = 0.f, ay = 0.f, az = 0.f, aw = 0.f;
        #pragma unroll
        for (int h = 0; h < 16; h++) {
            if ((mm >> h) & 1u) {
                float4 v = *(const float4*)(xb + h * HSTRIDE);
                ax += v.x; ay += v.y; az += v.z; aw += v.w;
            } else if ((fb >> h) & 1u) {
                float4 v = *(const float4*)(xb + h * HSTRIDE);
                int vb = s_base[h * 44 + w];
                float* o = out + (size_t)(vb >> 16) * OUT_PER_B + (vb & 65535);
                atomicAdd(o + (size_t)(c4*4 + 0) * GRID_HW, v.x);
                atomicAdd(o + (size_t)(c4*4 + 1) * GRID_HW, v.y);
                atomicAdd(o + (size_t)(c4*4 + 2) * GRID_HW, v.z);
                atomicAdd(o + (size_t)(c4*4 + 3) * GRID_HW, v.w);
            }
        }
        if (mm) {
            int vb = s_colbase[w];
            float* o = out + (size_t)(vb >> 16) * OUT_PER_B + (vb & 65535);
            atomicAdd(o + (size_t)(c4*4 + 0) * GRID_HW, ax);
            atomicAdd(o + (size_t)(c4*4 + 1) * GRID_HW, ay);
            atomicAdd(o + (size_t)(c4*4 + 2) * GRID_HW, az);
            atomicAdd(o + (size_t)(c4*4 + 3) * GRID_HW, aw);
        }
    }
}

extern "C" void kernel_launch(void* const* d_in, const int* in_sizes, int n_in,
                              void* d_out, int out_size, void* d_ws, size_t ws_size,
                              hipStream_t stream) {
    const float* x          = (const float*)d_in[0];
    const float* rots       = (const float*)d_in[1];
    const float* trans      = (const float*)d_in[2];
    const float* intrins    = (const float*)d_in[3];
    const float* post_rots  = (const float*)d_in[4];
    const float* post_trans = (const float*)d_in[5];
    float* out = (float*)d_out;

    if (ws_size >= (size_t)WS_NEED) {
        float*    P       = (float*)d_ws;
        int*      nxt     = (int*)((char*)d_ws + NEXT_OFF);
        int*      head    = (int*)((char*)d_ws + HEAD_OFF);
        int*      counter = (int*)((char*)d_ws + CNT_OFF);
        unsigned* meta    = (unsigned*)((char*)d_ws + META_OFF);
        init_heads<<<128, 256, 0, stream>>>((int4*)head, counter);
        geom_cols<<<99, 256, 0, stream>>>(rots, trans, intrins,
                                          post_rots, post_trans,
                                          nxt, head, counter, meta);
        reduce_kernel<<<1024, 256, 0, stream>>>(x, meta, counter, P);
        gather_tiled<<<2048, 256, 0, stream>>>(P, nxt, head, out);
    } else if (ws_size >= 12 * 24 * sizeof(double)) {
        double* tw = (double*)d_ws;
        zero_kernel<<<2560, 256, 0, stream>>>((float4*)out, out_size / 16);
        prep_kernel<<<1, 64, 0, stream>>>(rots, trans, intrins, post_rots, post_trans, tw);
        scatter_direct_kernel<<<576, 256, 0, stream>>>(x, tw, out);
    }
}